// Round 12
// baseline (1268.280 us; speedup 1.0000x reference)
//
#include <hip/hip_runtime.h>
#include <cmath>

#define TBUF 1024
#define RCH  256

typedef __bf16 bf16x8 __attribute__((ext_vector_type(8)));
typedef float  f32x4  __attribute__((ext_vector_type(4)));

__device__ inline unsigned short f2bf(float f) {
  unsigned u = __builtin_bit_cast(unsigned, f);
  u += 0x7FFFu + ((u >> 16) & 1u);
  return (unsigned short)(u >> 16);
}

// ---------------- merged weight transforms (one dispatch) ----------------
// blocks [0,16384): Wb   fgb   (32*512*256 items)
// blocks [16384,18432): Wrb   resb (524288 items, float4-wise)
// blocks [18432,22528): wskT  skip (1048576 items)
// blocks [22528,22592): w2    w_in transpose (16384 items)
__global__ __launch_bounds__(256) void prep(
    const float* __restrict__ wf, const float* __restrict__ wg,
    const float* __restrict__ wr, const float* __restrict__ wsk,
    const float* __restrict__ w_in,
    unsigned short* __restrict__ Wb, unsigned short* __restrict__ Wrb,
    float* __restrict__ wskT, float* __restrict__ w2)
{
  const int bid = blockIdx.x;
  const int tid = threadIdx.x;
  if (bid < 16384) {
    int idx = bid * 256 + tid;
    int c  = idx & 255;
    int op = (idx >> 8) & 511;
    int i  = idx >> 17;
    int o  = op & 255;
    const float* src = (op < 256) ? wf : wg;
    const float2 v = *(const float2*)&src[(((size_t)i * 256 + o) * 256 + c) << 1];
    unsigned short* dst = Wb + ((size_t)i * 512 + op) * 512;
    dst[c]       = f2bf(v.y);   // current tap (k=1)
    dst[256 + c] = f2bf(v.x);   // previous tap (k=0)
  } else if (bid < 18432) {
    int idx = (bid - 16384) * 256 + tid;
    float4 v = ((const float4*)wr)[idx];
    uint2 o;
    o.x = (unsigned)f2bf(v.x) | ((unsigned)f2bf(v.y) << 16);
    o.y = (unsigned)f2bf(v.z) | ((unsigned)f2bf(v.w) << 16);
    ((uint2*)Wrb)[idx] = o;
  } else if (bid < 22528) {
    int idx = (bid - 18432) * 256 + tid;
    int s = idx & 127;
    int c = (idx >> 7) & 255;
    int i = idx >> 15;
    wskT[idx] = wsk[(i * 128 + s) * 256 + c];
  } else {
    int idx = (bid - 22528) * 256 + tid;
    int r = idx & 255;
    int fk = idx >> 8;
    int f = fk & 31, k = fk >> 5;
    w2[idx] = w_in[r * 64 + f * 2 + k];
  }
}

// ---------------- input conv (F=32 -> R=256, K=2, d=1) ----------------
__global__ __launch_bounds__(256) void in_conv(
    const float* __restrict__ X, const float* __restrict__ w2,
    const float* __restrict__ b_in, float* __restrict__ xb,
    unsigned short* __restrict__ xbb)
{
  const int bid   = blockIdx.x;
  const int b     = bid & 15;
  const int chunk = bid >> 4;
  const int r     = threadIdx.x;
  __shared__ float Xs[17][32];
  const int tt0 = chunk << 4;
  const int t0  = tt0 + 1024;
  for (int idx = r; idx < 17 * 32; idx += 256) {
    int row = idx >> 5, f = idx & 31;
    Xs[row][f] = X[((size_t)b * 2048 + (t0 - 1 + row)) * 32 + f];
  }
  __syncthreads();
  float w0[32], w1[32];
  #pragma unroll
  for (int f = 0; f < 32; ++f) {
    w0[f] = w2[f * 256 + r];
    w1[f] = w2[(32 + f) * 256 + r];
  }
  const float bias = b_in[r];
  float4 prev[8], cur[8];
  #pragma unroll
  for (int q = 0; q < 8; ++q) prev[q] = *(const float4*)&Xs[0][q * 4];
  #pragma unroll
  for (int j = 0; j < 16; ++j) {
    #pragma unroll
    for (int q = 0; q < 8; ++q) cur[q] = *(const float4*)&Xs[j + 1][q * 4];
    float a = bias;
    #pragma unroll
    for (int q = 0; q < 8; ++q) {
      a = fmaf(w0[q*4+0], prev[q].x, a); a = fmaf(w1[q*4+0], cur[q].x, a);
      a = fmaf(w0[q*4+1], prev[q].y, a); a = fmaf(w1[q*4+1], cur[q].y, a);
      a = fmaf(w0[q*4+2], prev[q].z, a); a = fmaf(w1[q*4+2], cur[q].z, a);
      a = fmaf(w0[q*4+3], prev[q].w, a); a = fmaf(w1[q*4+3], cur[q].w, a);
    }
    int tt = tt0 + j;
    size_t off = ((size_t)b * TBUF + tt) * RCH + r;
    if (tt < 3) { xb[off] = 0.f; xbb[off] = 0; }
    else        { xb[off] = a;   xbb[off] = f2bf(a); }
    #pragma unroll
    for (int q = 0; q < 8; ++q) prev[q] = cur[q];
  }
}

// ---------------- fused layer ----------------
// 512 thr = 8 waves, M=64 rows, full N. Grid = tiles*16 <= 256 blocks = 1 block/CU
// ALWAYS, so min-waves=2 (256-VGPR budget) costs no occupancy; res-B hoist and
// deep load pipelining are now register-affordable (r4/r8 spills were the 128-cap).
__global__ __launch_bounds__(512, 2) void layer_fused(
    const unsigned short* __restrict__ xbb_r, float* __restrict__ xb,
    unsigned short* __restrict__ xbb_w,
    const unsigned short* __restrict__ Wb,   // [512][512] bf16
    const unsigned short* __restrict__ Wrb,  // [256][256] bf16
    const float* __restrict__ bF, const float* __restrict__ bG,
    const float* __restrict__ bR,
    int dd, int t_lo, float* __restrict__ fxs_i)
{
  __shared__ __align__(16) unsigned short As[64 * 520];   // 66,560 B; z aliases
  const int bid  = blockIdx.x;
  const int b    = bid & 15;
  const int tile = bid >> 4;
  const int tid  = threadIdx.x;
  const int w    = tid >> 6;
  const int lane = tid & 63;
  const int l15  = lane & 15;
  const int lk8  = (lane >> 4) << 3;
  const int rr0  = (lane >> 4) << 2;
  const int tt0  = t_lo + tile * 64;
  const unsigned short* xB = xbb_r + ((size_t)b << 18);

  // ---- stage A tile via global_load_lds: 64 rows x 512 k
  {
    const int c   = lane;
    const int tap = c >> 5;
    const int cg  = (c & 31) << 3;
    #pragma unroll
    for (int it = 0; it < 8; ++it) {
      int r = it * 8 + w;
      int tt = tt0 + r - tap * dd;
      tt = min(max(tt, 0), 1023);
      __builtin_amdgcn_global_load_lds(
          (const __attribute__((address_space(1))) unsigned int*)
              (xB + ((size_t)tt << 8) + cg),
          (__attribute__((address_space(3))) unsigned int*)
              ((char*)As + r * 1040),
          16, 0, 0);
    }
  }
  __syncthreads();

  // ---- conv GEMM (no barriers): per wave 64(M) x {32 f + 32 g}
  f32x4 accf[4][2] = {};
  f32x4 accg[4][2] = {};
  const unsigned short* wf0 = Wb + (size_t)(32 * w + l15) * 512 + lk8;
  const unsigned short* wf1 = wf0 + (size_t)16 * 512;
  const unsigned short* wg0 = wf0 + (size_t)256 * 512;
  const unsigned short* wg1 = wf0 + (size_t)272 * 512;
  #pragma unroll 4
  for (int kc = 0; kc < 16; ++kc) {
    const int k0 = kc * 32;
    uint4 ubf0 = *(const uint4*)(wf0 + k0);
    uint4 ubf1 = *(const uint4*)(wf1 + k0);
    uint4 ubg0 = *(const uint4*)(wg0 + k0);
    uint4 ubg1 = *(const uint4*)(wg1 + k0);
    const int colb = (k0 + lk8) * 2;
    bf16x8 a[4];
    #pragma unroll
    for (int mf = 0; mf < 4; ++mf)
      a[mf] = *(const bf16x8*)((const char*)As + (mf * 16 + l15) * 1040 + colb);
    bf16x8 vf0 = __builtin_bit_cast(bf16x8, ubf0);
    bf16x8 vf1 = __builtin_bit_cast(bf16x8, ubf1);
    bf16x8 vg0 = __builtin_bit_cast(bf16x8, ubg0);
    bf16x8 vg1 = __builtin_bit_cast(bf16x8, ubg1);
    #pragma unroll
    for (int mf = 0; mf < 4; ++mf) {
      accf[mf][0] = __builtin_amdgcn_mfma_f32_16x16x32_bf16(a[mf], vf0, accf[mf][0], 0, 0, 0);
      accf[mf][1] = __builtin_amdgcn_mfma_f32_16x16x32_bf16(a[mf], vf1, accf[mf][1], 0, 0, 0);
      accg[mf][0] = __builtin_amdgcn_mfma_f32_16x16x32_bf16(a[mf], vg0, accg[mf][0], 0, 0, 0);
      accg[mf][1] = __builtin_amdgcn_mfma_f32_16x16x32_bf16(a[mf], vg1, accg[mf][1], 0, 0, 0);
    }
  }

  // ---- hoist res-GEMM B loads (safe at 256-VGPR budget; latency hides
  //      under the barrier + gate epilogue)
  const unsigned short* wr0 = Wrb + (size_t)(32 * w + l15) * 256 + lk8;
  const unsigned short* wr1 = wr0 + (size_t)16 * 256;
  uint4 urr[8][2];
  #pragma unroll
  for (int kc = 0; kc < 8; ++kc) {
    urr[kc][0] = *(const uint4*)(wr0 + kc * 32);
    urr[kc][1] = *(const uint4*)(wr1 + kc * 32);
  }
  __syncthreads();   // all As reads done -> safe to overwrite with z

  // ---- gate epilogue: z = tanh(f+bf) * sigmoid(g+bg) -> LDS (aliased)
  unsigned short* Zs = As;
  const float bfv[2] = { bF[32 * w + l15], bF[32 * w + 16 + l15] };
  const float bgv[2] = { bG[32 * w + l15], bG[32 * w + 16 + l15] };
  #pragma unroll
  for (int mf = 0; mf < 4; ++mf)
    #pragma unroll
    for (int nf = 0; nf < 2; ++nf) {
      int col = 32 * w + nf * 16 + l15;
      #pragma unroll
      for (int j = 0; j < 4; ++j) {
        int row = mf * 16 + rr0 + j;
        float pf = accf[mf][nf][j] + bfv[nf];
        float pg = accg[mf][nf][j] + bgv[nf];
        float e2 = __expf(2.f * pf);
        float th = 1.f - 2.f / (e2 + 1.f);
        float sg = 1.f / (1.f + __expf(-pg));
        *(unsigned short*)((char*)Zs + row * 528 + col * 2) = f2bf(th * sg);
      }
    }
  __syncthreads();

  // ---- hoist fp32-master loads (independent of z; latency hides under res GEMM)
  float* xBf = xb + ((size_t)b << 18);
  float xo_pre[4][4][2];
  #pragma unroll
  for (int mf = 0; mf < 4; ++mf)
    #pragma unroll
    for (int j = 0; j < 4; ++j) {
      int tt = min(tt0 + mf * 16 + rr0 + j, 1023);
      #pragma unroll
      for (int nf = 0; nf < 2; ++nf) {
        int o = 32 * w + nf * 16 + l15;
        xo_pre[mf][j][nf] = xBf[((size_t)tt << 8) + o];
      }
    }

  // ---- res GEMM: per wave 64(M) x 32(N), K=256 from z-LDS (B from urr)
  f32x4 acc[4][2] = {};
  #pragma unroll 4
  for (int kc = 0; kc < 8; ++kc) {
    const int colb = (kc * 32 + lk8) * 2;
    bf16x8 a[4];
    #pragma unroll
    for (int mf = 0; mf < 4; ++mf)
      a[mf] = *(const bf16x8*)((const char*)Zs + (mf * 16 + l15) * 528 + colb);
    bf16x8 v0 = __builtin_bit_cast(bf16x8, urr[kc][0]);
    bf16x8 v1 = __builtin_bit_cast(bf16x8, urr[kc][1]);
    #pragma unroll
    for (int mf = 0; mf < 4; ++mf) {
      acc[mf][0] = __builtin_amdgcn_mfma_f32_16x16x32_bf16(a[mf], v0, acc[mf][0], 0, 0, 0);
      acc[mf][1] = __builtin_amdgcn_mfma_f32_16x16x32_bf16(a[mf], v1, acc[mf][1], 0, 0, 0);
    }
  }

  // ---- residual epilogue: fx = acc + bR; x += fx; bf16 mirror; fx snapshot
  const float brv[2] = { bR[32 * w + l15], bR[32 * w + 16 + l15] };
  unsigned short* xBb = xbb_w + ((size_t)b << 18);
  #pragma unroll
  for (int mf = 0; mf < 4; ++mf)
    #pragma unroll
    for (int j = 0; j < 4; ++j) {
      int tt = tt0 + mf * 16 + rr0 + j;
      if (tt > 1023) continue;
      #pragma unroll
      for (int nf = 0; nf < 2; ++nf) {
        int o = 32 * w + nf * 16 + l15;
        size_t off = ((size_t)tt << 8) + o;
        float fx = acc[mf][nf][j] + brv[nf];
        float xn = xo_pre[mf][j][nf] + fx;
        xBf[off] = xn;
        xBb[off] = f2bf(xn);
        if (tt == 1023) fxs_i[(size_t)b * 256 + o] = fx;
      }
    }
}

// ---------------- head ----------------
__global__ __launch_bounds__(128) void skip_partial(
    const float* __restrict__ fxs, const float* __restrict__ wskT,
    const float* __restrict__ b_skip, float* __restrict__ part)
{
  int i = blockIdx.x, b = blockIdx.y, s = threadIdx.x;
  __shared__ float fxsh[256];
  fxsh[s]       = fxs[((size_t)i * 16 + b) * 256 + s];
  fxsh[s + 128] = fxs[((size_t)i * 16 + b) * 256 + s + 128];
  __syncthreads();
  float a = b_skip[i * 128 + s];
  const float* wp = wskT + (size_t)i * 256 * 128 + s;
  #pragma unroll 4
  for (int c = 0; c < 256; c++)
    a = fmaf(wp[c * 128], fxsh[c], a);
  part[((size_t)i * 16 + b) * 128 + s] = a;
}

__global__ __launch_bounds__(128) void head2(
    const float* __restrict__ part, const float* __restrict__ w_o1,
    const float* __restrict__ b_o1, const float* __restrict__ w_o2,
    const float* __restrict__ b_o2, const float* __restrict__ w_lin,
    const float* __restrict__ b_lin, const float* __restrict__ Xex,
    float* __restrict__ out)
{
  int b = blockIdx.x, tid = threadIdx.x;
  __shared__ float sk[128];
  __shared__ float h1[64];
  __shared__ float hc[80];
  float a = 0.f;
  for (int i = 0; i < 32; i++) a += part[((size_t)i * 16 + b) * 128 + tid];
  sk[tid] = fmaxf(a, 0.f);
  __syncthreads();
  if (tid < 64) {
    float a1 = b_o1[tid];
    for (int s = 0; s < 128; s++) a1 = fmaf(w_o1[tid * 128 + s], sk[s], a1);
    h1[tid] = fmaxf(a1, 0.f);
  }
  __syncthreads();
  if (tid < 64) {
    float a2 = b_o2[tid];
    for (int j = 0; j < 64; j++) a2 = fmaf(w_o2[tid * 64 + j], h1[j], a2);
    hc[tid] = fmaxf(a2, 0.f);
  }
  if (tid >= 64 && tid < 80) hc[tid] = fmaxf(Xex[b * 16 + (tid - 64)], 0.f);
  __syncthreads();
  if (tid < 24) {
    float a3 = b_lin[tid];
    for (int j = 0; j < 80; j++) a3 = fmaf(w_lin[tid * 80 + j], hc[j], a3);
    out[b * 24 + tid] = a3;
  }
}

extern "C" void kernel_launch(void* const* d_in, const int* in_sizes, int n_in,
                              void* d_out, int out_size, void* d_ws, size_t ws_size,
                              hipStream_t stream)
{
  (void)in_sizes; (void)n_in; (void)out_size; (void)ws_size;
  const float* X     = (const float*)d_in[0];
  const float* Xex   = (const float*)d_in[1];
  const float* w_in  = (const float*)d_in[2];
  const float* b_in  = (const float*)d_in[3];
  const float* w_f   = (const float*)d_in[4];
  const float* b_f   = (const float*)d_in[5];
  const float* w_g   = (const float*)d_in[6];
  const float* b_g   = (const float*)d_in[7];
  const float* w_r   = (const float*)d_in[8];
  const float* b_r   = (const float*)d_in[9];
  const float* w_s   = (const float*)d_in[10];
  const float* b_s   = (const float*)d_in[11];
  const float* w_o1  = (const float*)d_in[12];
  const float* b_o1  = (const float*)d_in[13];
  const float* w_o2  = (const float*)d_in[14];
  const float* b_o2  = (const float*)d_in[15];
  const float* w_lin = (const float*)d_in[16];
  const float* b_lin = (const float*)d_in[17];

  float* ws   = (float*)d_ws;
  float* wskT = ws;                        // 1,048,576 f
  float* xb   = wskT + 1048576;            // 4,194,304 f
  float* fxs  = xb   + 4194304;            // 131,072 f
  float* part = fxs  + 131072;             // 65,536 f
  float* w2   = part + 65536;              // 16,384 f
  unsigned short* Wb   = (unsigned short*)(w2 + 16384);    // 8,388,608 us
  unsigned short* Wrb  = Wb   + 8388608;   // 2,097,152 us
  unsigned short* xbbA = Wrb  + 2097152;   // 4,194,304 us
  unsigned short* xbbB = xbbA + 4194304;   // 4,194,304 us

  prep<<<22592, 256, 0, stream>>>(w_f, w_g, w_r, w_s, w_in, Wb, Wrb, wskT, w2);
  in_conv<<<1024, 256, 0, stream>>>(X, w2, b_in, xb, xbbA);

  // suffix-window sizes: w[i] = w[i+1] + 2^(i%8), w[32] = 1
  static const int wI[33] = {1021,1020,1018,1014,1006,990,958,894,
                             766,765,763,759,751,735,703,639,
                             511,510,508,504,496,480,448,384,
                             256,255,253,249,241,225,193,129,1};
  for (int i = 0; i < 32; i++) {
    int dd    = 1 << (i & 7);
    int Wout  = wI[i + 1];
    int t_lo  = TBUF - Wout;
    int tiles = (Wout + 63) / 64;
    unsigned short* xin  = (i & 1) ? xbbB : xbbA;
    unsigned short* xout = (i & 1) ? xbbA : xbbB;
    layer_fused<<<tiles * 16, 512, 0, stream>>>(
        xin, xb, xout,
        Wb + (size_t)i * 512 * 512, Wrb + (size_t)i * 256 * 256,
        b_f + i * 256, b_g + i * 256, b_r + i * 256,
        dd, t_lo, fxs + (size_t)i * 16 * 256);
  }
  skip_partial<<<dim3(32, 16), 128, 0, stream>>>(fxs, wskT, b_s, part);
  head2<<<16, 128, 0, stream>>>(part, w_o1, b_o1, w_o2, b_o2, w_lin, b_lin, Xex, (float*)d_out);
}

// Round 13
// 1003.406 us; speedup vs baseline: 1.2640x; 1.2640x over previous
//
#include <hip/hip_runtime.h>
#include <cmath>

#define TBUF 1024
#define RCH  256

typedef __bf16 bf16x8 __attribute__((ext_vector_type(8)));
typedef float  f32x4  __attribute__((ext_vector_type(4)));

__device__ inline unsigned short f2bf(float f) {
  unsigned u = __builtin_bit_cast(unsigned, f);
  u += 0x7FFFu + ((u >> 16) & 1u);
  return (unsigned short)(u >> 16);
}

// ---------------- merged weight transforms (one dispatch) ----------------
__global__ __launch_bounds__(256) void prep(
    const float* __restrict__ wf, const float* __restrict__ wg,
    const float* __restrict__ wr, const float* __restrict__ wsk,
    const float* __restrict__ w_in,
    unsigned short* __restrict__ Wb, unsigned short* __restrict__ Wrb,
    float* __restrict__ wskT, float* __restrict__ w2)
{
  const int bid = blockIdx.x;
  const int tid = threadIdx.x;
  if (bid < 16384) {
    int idx = bid * 256 + tid;
    int c  = idx & 255;
    int op = (idx >> 8) & 511;
    int i  = idx >> 17;
    int o  = op & 255;
    const float* src = (op < 256) ? wf : wg;
    const float2 v = *(const float2*)&src[(((size_t)i * 256 + o) * 256 + c) << 1];
    unsigned short* dst = Wb + ((size_t)i * 512 + op) * 512;
    dst[c]       = f2bf(v.y);   // current tap (k=1)
    dst[256 + c] = f2bf(v.x);   // previous tap (k=0)
  } else if (bid < 18432) {
    int idx = (bid - 16384) * 256 + tid;
    float4 v = ((const float4*)wr)[idx];
    uint2 o;
    o.x = (unsigned)f2bf(v.x) | ((unsigned)f2bf(v.y) << 16);
    o.y = (unsigned)f2bf(v.z) | ((unsigned)f2bf(v.w) << 16);
    ((uint2*)Wrb)[idx] = o;
  } else if (bid < 22528) {
    int idx = (bid - 18432) * 256 + tid;
    int s = idx & 127;
    int c = (idx >> 7) & 255;
    int i = idx >> 15;
    wskT[idx] = wsk[(i * 128 + s) * 256 + c];
  } else {
    int idx = (bid - 22528) * 256 + tid;
    int r = idx & 255;
    int fk = idx >> 8;
    int f = fk & 31, k = fk >> 5;
    w2[idx] = w_in[r * 64 + f * 2 + k];
  }
}

// ---------------- input conv (F=32 -> R=256, K=2, d=1) ----------------
__global__ __launch_bounds__(256) void in_conv(
    const float* __restrict__ X, const float* __restrict__ w2,
    const float* __restrict__ b_in, float* __restrict__ xb,
    unsigned short* __restrict__ xbb)
{
  const int bid   = blockIdx.x;
  const int b     = bid & 15;
  const int chunk = bid >> 4;
  const int r     = threadIdx.x;
  __shared__ float Xs[17][32];
  const int tt0 = chunk << 4;
  const int t0  = tt0 + 1024;
  for (int idx = r; idx < 17 * 32; idx += 256) {
    int row = idx >> 5, f = idx & 31;
    Xs[row][f] = X[((size_t)b * 2048 + (t0 - 1 + row)) * 32 + f];
  }
  __syncthreads();
  float w0[32], w1[32];
  #pragma unroll
  for (int f = 0; f < 32; ++f) {
    w0[f] = w2[f * 256 + r];
    w1[f] = w2[(32 + f) * 256 + r];
  }
  const float bias = b_in[r];
  float4 prev[8], cur[8];
  #pragma unroll
  for (int q = 0; q < 8; ++q) prev[q] = *(const float4*)&Xs[0][q * 4];
  #pragma unroll
  for (int j = 0; j < 16; ++j) {
    #pragma unroll
    for (int q = 0; q < 8; ++q) cur[q] = *(const float4*)&Xs[j + 1][q * 4];
    float a = bias;
    #pragma unroll
    for (int q = 0; q < 8; ++q) {
      a = fmaf(w0[q*4+0], prev[q].x, a); a = fmaf(w1[q*4+0], cur[q].x, a);
      a = fmaf(w0[q*4+1], prev[q].y, a); a = fmaf(w1[q*4+1], cur[q].y, a);
      a = fmaf(w0[q*4+2], prev[q].z, a); a = fmaf(w1[q*4+2], cur[q].z, a);
      a = fmaf(w0[q*4+3], prev[q].w, a); a = fmaf(w1[q*4+3], cur[q].w, a);
    }
    int tt = tt0 + j;
    size_t off = ((size_t)b * TBUF + tt) * RCH + r;
    if (tt < 3) { xb[off] = 0.f; xbb[off] = 0; }
    else        { xb[off] = a;   xbb[off] = f2bf(a); }
    #pragma unroll
    for (int q = 0; q < 8; ++q) prev[q] = cur[q];
  }
}

// ---------------- fused layer: 1024 thr = 16 waves (2x latency hiding) ----------------
// M=64 rows, full N. Wave w owns 16 f-cols + 16 g-cols (conv), 16 cols (res).
// A-tile via global_load_lds, odd-stride LDS rows. Res-B IN-LOOP (hoist -> scratch,
// proven r4/r8/r12). xo_pre hoist kept (r11-verified safe). 1 block/CU, 16 waves/CU.
__global__ __launch_bounds__(1024, 4) void layer_fused(
    const unsigned short* __restrict__ xbb_r, float* __restrict__ xb,
    unsigned short* __restrict__ xbb_w,
    const unsigned short* __restrict__ Wb,   // [512][512] bf16
    const unsigned short* __restrict__ Wrb,  // [256][256] bf16
    const float* __restrict__ bF, const float* __restrict__ bG,
    const float* __restrict__ bR,
    int dd, int t_lo, float* __restrict__ fxs_i)
{
  __shared__ __align__(16) unsigned short As[64 * 520];   // 66,560 B; z aliases
  const int bid  = blockIdx.x;
  const int b    = bid & 15;
  const int tile = bid >> 4;
  const int tid  = threadIdx.x;
  const int w    = tid >> 6;          // 0..15
  const int lane = tid & 63;
  const int l15  = lane & 15;
  const int lk8  = (lane >> 4) << 3;
  const int rr0  = (lane >> 4) << 2;
  const int tt0  = t_lo + tile * 64;
  const unsigned short* xB = xbb_r + ((size_t)b << 18);

  // ---- stage A tile via global_load_lds: 64 rows x 512 k (16 waves, 4 rows each)
  {
    const int c   = lane;
    const int tap = c >> 5;
    const int cg  = (c & 31) << 3;
    #pragma unroll
    for (int it = 0; it < 4; ++it) {
      int r = it * 16 + w;
      int tt = tt0 + r - tap * dd;
      tt = min(max(tt, 0), 1023);
      __builtin_amdgcn_global_load_lds(
          (const __attribute__((address_space(1))) unsigned int*)
              (xB + ((size_t)tt << 8) + cg),
          (__attribute__((address_space(3))) unsigned int*)
              ((char*)As + r * 1040),
          16, 0, 0);
    }
  }
  __syncthreads();

  // ---- conv GEMM: per wave 64(M) x {16 f + 16 g}
  f32x4 accf[4] = {};
  f32x4 accg[4] = {};
  const unsigned short* wf0 = Wb + (size_t)(16 * w + l15) * 512 + lk8;
  const unsigned short* wg0 = wf0 + (size_t)256 * 512;
  #pragma unroll 4
  for (int kc = 0; kc < 16; ++kc) {
    const int k0 = kc * 32;
    uint4 ubf0 = *(const uint4*)(wf0 + k0);
    uint4 ubg0 = *(const uint4*)(wg0 + k0);
    const int colb = (k0 + lk8) * 2;
    bf16x8 a[4];
    #pragma unroll
    for (int mf = 0; mf < 4; ++mf)
      a[mf] = *(const bf16x8*)((const char*)As + (mf * 16 + l15) * 1040 + colb);
    bf16x8 vf0 = __builtin_bit_cast(bf16x8, ubf0);
    bf16x8 vg0 = __builtin_bit_cast(bf16x8, ubg0);
    #pragma unroll
    for (int mf = 0; mf < 4; ++mf) {
      accf[mf] = __builtin_amdgcn_mfma_f32_16x16x32_bf16(a[mf], vf0, accf[mf], 0, 0, 0);
      accg[mf] = __builtin_amdgcn_mfma_f32_16x16x32_bf16(a[mf], vg0, accg[mf], 0, 0, 0);
    }
  }
  __syncthreads();   // all As reads done -> safe to overwrite with z

  // ---- gate epilogue: z = tanh(f+bf) * sigmoid(g+bg) -> LDS (aliased)
  unsigned short* Zs = As;
  const int col = 16 * w + l15;
  const float bfv = bF[col];
  const float bgv = bG[col];
  #pragma unroll
  for (int mf = 0; mf < 4; ++mf)
    #pragma unroll
    for (int j = 0; j < 4; ++j) {
      int row = mf * 16 + rr0 + j;
      float pf = accf[mf][j] + bfv;
      float pg = accg[mf][j] + bgv;
      float e2 = __expf(2.f * pf);
      float th = 1.f - 2.f / (e2 + 1.f);
      float sg = 1.f / (1.f + __expf(-pg));
      *(unsigned short*)((char*)Zs + row * 528 + col * 2) = f2bf(th * sg);
    }
  __syncthreads();

  // ---- hoist fp32-master loads (independent of z; latency hides under res GEMM)
  float* xBf = xb + ((size_t)b << 18);
  float xo_pre[4][4];
  #pragma unroll
  for (int mf = 0; mf < 4; ++mf)
    #pragma unroll
    for (int j = 0; j < 4; ++j) {
      int tt = min(tt0 + mf * 16 + rr0 + j, 1023);
      xo_pre[mf][j] = xBf[((size_t)tt << 8) + col];
    }

  // ---- res GEMM: per wave 64(M) x 16(N), K=256 from z-LDS (B in-loop)
  f32x4 acc[4] = {};
  const unsigned short* wr0 = Wrb + (size_t)(16 * w + l15) * 256 + lk8;
  #pragma unroll 4
  for (int kc = 0; kc < 8; ++kc) {
    uint4 ur0 = *(const uint4*)(wr0 + kc * 32);
    const int colb = (kc * 32 + lk8) * 2;
    bf16x8 a[4];
    #pragma unroll
    for (int mf = 0; mf < 4; ++mf)
      a[mf] = *(const bf16x8*)((const char*)Zs + (mf * 16 + l15) * 528 + colb);
    bf16x8 v0 = __builtin_bit_cast(bf16x8, ur0);
    #pragma unroll
    for (int mf = 0; mf < 4; ++mf)
      acc[mf] = __builtin_amdgcn_mfma_f32_16x16x32_bf16(a[mf], v0, acc[mf], 0, 0, 0);
  }

  // ---- residual epilogue: fx = acc + bR; x += fx; bf16 mirror; fx snapshot
  const float brv = bR[col];
  unsigned short* xBb = xbb_w + ((size_t)b << 18);
  #pragma unroll
  for (int mf = 0; mf < 4; ++mf)
    #pragma unroll
    for (int j = 0; j < 4; ++j) {
      int tt = tt0 + mf * 16 + rr0 + j;
      if (tt > 1023) continue;
      size_t off = ((size_t)tt << 8) + col;
      float fx = acc[mf][j] + brv;
      float xn = xo_pre[mf][j] + fx;
      xBf[off] = xn;
      xBb[off] = f2bf(xn);
      if (tt == 1023) fxs_i[(size_t)b * 256 + col] = fx;
    }
}

// ---------------- head ----------------
__global__ __launch_bounds__(128) void skip_partial(
    const float* __restrict__ fxs, const float* __restrict__ wskT,
    const float* __restrict__ b_skip, float* __restrict__ part)
{
  int i = blockIdx.x, b = blockIdx.y, s = threadIdx.x;
  __shared__ float fxsh[256];
  fxsh[s]       = fxs[((size_t)i * 16 + b) * 256 + s];
  fxsh[s + 128] = fxs[((size_t)i * 16 + b) * 256 + s + 128];
  __syncthreads();
  float a = b_skip[i * 128 + s];
  const float* wp = wskT + (size_t)i * 256 * 128 + s;
  #pragma unroll 4
  for (int c = 0; c < 256; c++)
    a = fmaf(wp[c * 128], fxsh[c], a);
  part[((size_t)i * 16 + b) * 128 + s] = a;
}

__global__ __launch_bounds__(128) void head2(
    const float* __restrict__ part, const float* __restrict__ w_o1,
    const float* __restrict__ b_o1, const float* __restrict__ w_o2,
    const float* __restrict__ b_o2, const float* __restrict__ w_lin,
    const float* __restrict__ b_lin, const float* __restrict__ Xex,
    float* __restrict__ out)
{
  int b = blockIdx.x, tid = threadIdx.x;
  __shared__ float sk[128];
  __shared__ float h1[64];
  __shared__ float hc[80];
  float a = 0.f;
  for (int i = 0; i < 32; i++) a += part[((size_t)i * 16 + b) * 128 + tid];
  sk[tid] = fmaxf(a, 0.f);
  __syncthreads();
  if (tid < 64) {
    float a1 = b_o1[tid];
    for (int s = 0; s < 128; s++) a1 = fmaf(w_o1[tid * 128 + s], sk[s], a1);
    h1[tid] = fmaxf(a1, 0.f);
  }
  __syncthreads();
  if (tid < 64) {
    float a2 = b_o2[tid];
    for (int j = 0; j < 64; j++) a2 = fmaf(w_o2[tid * 64 + j], h1[j], a2);
    hc[tid] = fmaxf(a2, 0.f);
  }
  if (tid >= 64 && tid < 80) hc[tid] = fmaxf(Xex[b * 16 + (tid - 64)], 0.f);
  __syncthreads();
  if (tid < 24) {
    float a3 = b_lin[tid];
    for (int j = 0; j < 80; j++) a3 = fmaf(w_lin[tid * 80 + j], hc[j], a3);
    out[b * 24 + tid] = a3;
  }
}

extern "C" void kernel_launch(void* const* d_in, const int* in_sizes, int n_in,
                              void* d_out, int out_size, void* d_ws, size_t ws_size,
                              hipStream_t stream)
{
  (void)in_sizes; (void)n_in; (void)out_size; (void)ws_size;
  const float* X     = (const float*)d_in[0];
  const float* Xex   = (const float*)d_in[1];
  const float* w_in  = (const float*)d_in[2];
  const float* b_in  = (const float*)d_in[3];
  const float* w_f   = (const float*)d_in[4];
  const float* b_f   = (const float*)d_in[5];
  const float* w_g   = (const float*)d_in[6];
  const float* b_g   = (const float*)d_in[7];
  const float* w_r   = (const float*)d_in[8];
  const float* b_r   = (const float*)d_in[9];
  const float* w_s   = (const float*)d_in[10];
  const float* b_s   = (const float*)d_in[11];
  const float* w_o1  = (const float*)d_in[12];
  const float* b_o1  = (const float*)d_in[13];
  const float* w_o2  = (const float*)d_in[14];
  const float* b_o2  = (const float*)d_in[15];
  const float* w_lin = (const float*)d_in[16];
  const float* b_lin = (const float*)d_in[17];

  float* ws   = (float*)d_ws;
  float* wskT = ws;                        // 1,048,576 f
  float* xb   = wskT + 1048576;            // 4,194,304 f
  float* fxs  = xb   + 4194304;            // 131,072 f
  float* part = fxs  + 131072;             // 65,536 f
  float* w2   = part + 65536;              // 16,384 f
  unsigned short* Wb   = (unsigned short*)(w2 + 16384);    // 8,388,608 us
  unsigned short* Wrb  = Wb   + 8388608;   // 2,097,152 us
  unsigned short* xbbA = Wrb  + 2097152;   // 4,194,304 us
  unsigned short* xbbB = xbbA + 4194304;   // 4,194,304 us

  prep<<<22592, 256, 0, stream>>>(w_f, w_g, w_r, w_s, w_in, Wb, Wrb, wskT, w2);
  in_conv<<<1024, 256, 0, stream>>>(X, w2, b_in, xb, xbbA);

  // suffix-window sizes: w[i] = w[i+1] + 2^(i%8), w[32] = 1
  static const int wI[33] = {1021,1020,1018,1014,1006,990,958,894,
                             766,765,763,759,751,735,703,639,
                             511,510,508,504,496,480,448,384,
                             256,255,253,249,241,225,193,129,1};
  for (int i = 0; i < 32; i++) {
    int dd    = 1 << (i & 7);
    int Wout  = wI[i + 1];
    int t_lo  = TBUF - Wout;
    int tiles = (Wout + 63) / 64;
    unsigned short* xin  = (i & 1) ? xbbB : xbbA;
    unsigned short* xout = (i & 1) ? xbbA : xbbB;
    layer_fused<<<tiles * 16, 1024, 0, stream>>>(
        xin, xb, xout,
        Wb + (size_t)i * 512 * 512, Wrb + (size_t)i * 256 * 256,
        b_f + i * 256, b_g + i * 256, b_r + i * 256,
        dd, t_lo, fxs + (size_t)i * 16 * 256);
  }
  skip_partial<<<dim3(32, 16), 128, 0, stream>>>(fxs, wskT, b_s, part);
  head2<<<16, 128, 0, stream>>>(part, w_o1, b_o1, w_o2, b_o2, w_lin, b_lin, Xex, (float*)d_out);
}

// Round 14
// 997.779 us; speedup vs baseline: 1.2711x; 1.0056x over previous
//
#include <hip/hip_runtime.h>
#include <cmath>

#define TBUF 1024
#define RCH  256

typedef __bf16 bf16x8 __attribute__((ext_vector_type(8)));
typedef float  f32x4  __attribute__((ext_vector_type(4)));

__device__ inline unsigned short f2bf(float f) {
  unsigned u = __builtin_bit_cast(unsigned, f);
  u += 0x7FFFu + ((u >> 16) & 1u);
  return (unsigned short)(u >> 16);
}
__device__ inline float bf2f(unsigned short h) {
  unsigned u = ((unsigned)h) << 16;
  return __builtin_bit_cast(float, u);
}

// ---------------- merged weight transforms (one dispatch) ----------------
__global__ __launch_bounds__(256) void prep(
    const float* __restrict__ wf, const float* __restrict__ wg,
    const float* __restrict__ wr, const float* __restrict__ wsk,
    const float* __restrict__ w_in,
    unsigned short* __restrict__ Wb, unsigned short* __restrict__ Wrb,
    float* __restrict__ wskT, float* __restrict__ w2)
{
  const int bid = blockIdx.x;
  const int tid = threadIdx.x;
  if (bid < 16384) {
    int idx = bid * 256 + tid;
    int c  = idx & 255;
    int op = (idx >> 8) & 511;
    int i  = idx >> 17;
    int o  = op & 255;
    const float* src = (op < 256) ? wf : wg;
    const float2 v = *(const float2*)&src[(((size_t)i * 256 + o) * 256 + c) << 1];
    unsigned short* dst = Wb + ((size_t)i * 512 + op) * 512;
    dst[c]       = f2bf(v.y);   // current tap (k=1)
    dst[256 + c] = f2bf(v.x);   // previous tap (k=0)
  } else if (bid < 18432) {
    int idx = (bid - 16384) * 256 + tid;
    float4 v = ((const float4*)wr)[idx];
    uint2 o;
    o.x = (unsigned)f2bf(v.x) | ((unsigned)f2bf(v.y) << 16);
    o.y = (unsigned)f2bf(v.z) | ((unsigned)f2bf(v.w) << 16);
    ((uint2*)Wrb)[idx] = o;
  } else if (bid < 22528) {
    int idx = (bid - 18432) * 256 + tid;
    int s = idx & 127;
    int c = (idx >> 7) & 255;
    int i = idx >> 15;
    wskT[idx] = wsk[(i * 128 + s) * 256 + c];
  } else {
    int idx = (bid - 22528) * 256 + tid;
    int r = idx & 255;
    int fk = idx >> 8;
    int f = fk & 31, k = fk >> 5;
    w2[idx] = w_in[r * 64 + f * 2 + k];
  }
}

// ---------------- input conv (F=32 -> R=256, K=2, d=1) ----------------
// writes hi (bf16 mirror) + lo (bf16 low part); no fp32 master anymore.
__global__ __launch_bounds__(256) void in_conv(
    const float* __restrict__ X, const float* __restrict__ w2,
    const float* __restrict__ b_in, unsigned short* __restrict__ xbb,
    unsigned short* __restrict__ xlo)
{
  const int bid   = blockIdx.x;
  const int b     = bid & 15;
  const int chunk = bid >> 4;
  const int r     = threadIdx.x;
  __shared__ float Xs[17][32];
  const int tt0 = chunk << 4;
  const int t0  = tt0 + 1024;
  for (int idx = r; idx < 17 * 32; idx += 256) {
    int row = idx >> 5, f = idx & 31;
    Xs[row][f] = X[((size_t)b * 2048 + (t0 - 1 + row)) * 32 + f];
  }
  __syncthreads();
  float w0[32], w1[32];
  #pragma unroll
  for (int f = 0; f < 32; ++f) {
    w0[f] = w2[f * 256 + r];
    w1[f] = w2[(32 + f) * 256 + r];
  }
  const float bias = b_in[r];
  float4 prev[8], cur[8];
  #pragma unroll
  for (int q = 0; q < 8; ++q) prev[q] = *(const float4*)&Xs[0][q * 4];
  #pragma unroll
  for (int j = 0; j < 16; ++j) {
    #pragma unroll
    for (int q = 0; q < 8; ++q) cur[q] = *(const float4*)&Xs[j + 1][q * 4];
    float a = bias;
    #pragma unroll
    for (int q = 0; q < 8; ++q) {
      a = fmaf(w0[q*4+0], prev[q].x, a); a = fmaf(w1[q*4+0], cur[q].x, a);
      a = fmaf(w0[q*4+1], prev[q].y, a); a = fmaf(w1[q*4+1], cur[q].y, a);
      a = fmaf(w0[q*4+2], prev[q].z, a); a = fmaf(w1[q*4+2], cur[q].z, a);
      a = fmaf(w0[q*4+3], prev[q].w, a); a = fmaf(w1[q*4+3], cur[q].w, a);
    }
    int tt = tt0 + j;
    size_t off = ((size_t)b * TBUF + tt) * RCH + r;
    if (tt < 3) { xbb[off] = 0; xlo[off] = 0; }
    else {
      unsigned short hn = f2bf(a);
      xbb[off] = hn;
      xlo[off] = f2bf(a - bf2f(hn));
    }
    #pragma unroll
    for (int q = 0; q < 8; ++q) prev[q] = cur[q];
  }
}

// ---------------- fused layer: 1024 thr = 16 waves, split-precision residual -------
// M=64 rows, full N. x = hi + lo (two bf16); hi_old re-read from the A-tile LDS
// (tap-0 rows == epilogue rows) before z overwrites it; lo RMW'd in place.
// Res-B IN-LOOP (hoist -> scratch, r4/r8/r12). A-stage via global_load_lds.
__global__ __launch_bounds__(1024, 4) void layer_fused(
    const unsigned short* __restrict__ xbb_r, unsigned short* __restrict__ xbb_w,
    unsigned short* __restrict__ xlo,
    const unsigned short* __restrict__ Wb,   // [512][512] bf16
    const unsigned short* __restrict__ Wrb,  // [256][256] bf16
    const float* __restrict__ bF, const float* __restrict__ bG,
    const float* __restrict__ bR,
    int dd, int t_lo, float* __restrict__ fxs_i)
{
  __shared__ __align__(16) unsigned short As[64 * 520];   // 66,560 B; z aliases
  const int bid  = blockIdx.x;
  const int b    = bid & 15;
  const int tile = bid >> 4;
  const int tid  = threadIdx.x;
  const int w    = tid >> 6;          // 0..15
  const int lane = tid & 63;
  const int l15  = lane & 15;
  const int lk8  = (lane >> 4) << 3;
  const int rr0  = (lane >> 4) << 2;
  const int tt0  = t_lo + tile * 64;
  const unsigned short* xB = xbb_r + ((size_t)b << 18);

  // ---- stage A tile via global_load_lds: 64 rows x 512 k (16 waves, 4 rows each)
  {
    const int c   = lane;
    const int tap = c >> 5;
    const int cg  = (c & 31) << 3;
    #pragma unroll
    for (int it = 0; it < 4; ++it) {
      int r = it * 16 + w;
      int tt = tt0 + r - tap * dd;
      tt = min(max(tt, 0), 1023);
      __builtin_amdgcn_global_load_lds(
          (const __attribute__((address_space(1))) unsigned int*)
              (xB + ((size_t)tt << 8) + cg),
          (__attribute__((address_space(3))) unsigned int*)
              ((char*)As + r * 1040),
          16, 0, 0);
    }
  }
  __syncthreads();

  // ---- conv GEMM: per wave 64(M) x {16 f + 16 g}
  f32x4 accf[4] = {};
  f32x4 accg[4] = {};
  const unsigned short* wf0 = Wb + (size_t)(16 * w + l15) * 512 + lk8;
  const unsigned short* wg0 = wf0 + (size_t)256 * 512;
  #pragma unroll 4
  for (int kc = 0; kc < 16; ++kc) {
    const int k0 = kc * 32;
    uint4 ubf0 = *(const uint4*)(wf0 + k0);
    uint4 ubg0 = *(const uint4*)(wg0 + k0);
    const int colb = (k0 + lk8) * 2;
    bf16x8 a[4];
    #pragma unroll
    for (int mf = 0; mf < 4; ++mf)
      a[mf] = *(const bf16x8*)((const char*)As + (mf * 16 + l15) * 1040 + colb);
    bf16x8 vf0 = __builtin_bit_cast(bf16x8, ubf0);
    bf16x8 vg0 = __builtin_bit_cast(bf16x8, ubg0);
    #pragma unroll
    for (int mf = 0; mf < 4; ++mf) {
      accf[mf] = __builtin_amdgcn_mfma_f32_16x16x32_bf16(a[mf], vf0, accf[mf], 0, 0, 0);
      accg[mf] = __builtin_amdgcn_mfma_f32_16x16x32_bf16(a[mf], vg0, accg[mf], 0, 0, 0);
    }
  }

  // ---- re-read hi_old from the A-tile LDS (tap-0 region) BEFORE z overwrite
  const int col = 16 * w + l15;
  float hi_pre[4][4];
  #pragma unroll
  for (int mf = 0; mf < 4; ++mf)
    #pragma unroll
    for (int j = 0; j < 4; ++j) {
      int row = mf * 16 + rr0 + j;
      hi_pre[mf][j] = bf2f(*(const unsigned short*)((const char*)As + row * 1040 + col * 2));
    }
  __syncthreads();   // all As reads done -> safe to overwrite with z

  // ---- gate epilogue: z = tanh(f+bf) * sigmoid(g+bg) -> LDS (aliased)
  unsigned short* Zs = As;
  const float bfv = bF[col];
  const float bgv = bG[col];
  #pragma unroll
  for (int mf = 0; mf < 4; ++mf)
    #pragma unroll
    for (int j = 0; j < 4; ++j) {
      int row = mf * 16 + rr0 + j;
      float pf = accf[mf][j] + bfv;
      float pg = accg[mf][j] + bgv;
      float e2 = __expf(2.f * pf);
      float th = 1.f - 2.f / (e2 + 1.f);
      float sg = 1.f / (1.f + __expf(-pg));
      *(unsigned short*)((char*)Zs + row * 528 + col * 2) = f2bf(th * sg);
    }
  __syncthreads();

  // ---- hoist lo_old loads (independent of z; latency hides under res GEMM)
  unsigned short* xL = xlo + ((size_t)b << 18);
  float lo_pre[4][4];
  #pragma unroll
  for (int mf = 0; mf < 4; ++mf)
    #pragma unroll
    for (int j = 0; j < 4; ++j) {
      int tt = min(tt0 + mf * 16 + rr0 + j, 1023);
      lo_pre[mf][j] = bf2f(xL[((size_t)tt << 8) + col]);
    }

  // ---- res GEMM: per wave 64(M) x 16(N), K=256 from z-LDS (B in-loop)
  f32x4 acc[4] = {};
  const unsigned short* wr0 = Wrb + (size_t)(16 * w + l15) * 256 + lk8;
  #pragma unroll 4
  for (int kc = 0; kc < 8; ++kc) {
    uint4 ur0 = *(const uint4*)(wr0 + kc * 32);
    const int colb = (kc * 32 + lk8) * 2;
    bf16x8 a[4];
    #pragma unroll
    for (int mf = 0; mf < 4; ++mf)
      a[mf] = *(const bf16x8*)((const char*)Zs + (mf * 16 + l15) * 528 + colb);
    bf16x8 v0 = __builtin_bit_cast(bf16x8, ur0);
    #pragma unroll
    for (int mf = 0; mf < 4; ++mf)
      acc[mf] = __builtin_amdgcn_mfma_f32_16x16x32_bf16(a[mf], v0, acc[mf], 0, 0, 0);
  }

  // ---- residual epilogue: xn = (hi+lo) + fx; re-split to hi'/lo'; fx snapshot
  const float brv = bR[col];
  unsigned short* xBb = xbb_w + ((size_t)b << 18);
  #pragma unroll
  for (int mf = 0; mf < 4; ++mf)
    #pragma unroll
    for (int j = 0; j < 4; ++j) {
      int tt = tt0 + mf * 16 + rr0 + j;
      if (tt > 1023) continue;
      size_t off = ((size_t)tt << 8) + col;
      float fx = acc[mf][j] + brv;
      float xn = (hi_pre[mf][j] + lo_pre[mf][j]) + fx;
      unsigned short hn = f2bf(xn);
      xBb[off] = hn;
      xL[off]  = f2bf(xn - bf2f(hn));
      if (tt == 1023) fxs_i[(size_t)b * 256 + col] = fx;
    }
}

// ---------------- head ----------------
__global__ __launch_bounds__(128) void skip_partial(
    const float* __restrict__ fxs, const float* __restrict__ wskT,
    const float* __restrict__ b_skip, float* __restrict__ part)
{
  int i = blockIdx.x, b = blockIdx.y, s = threadIdx.x;
  __shared__ float fxsh[256];
  fxsh[s]       = fxs[((size_t)i * 16 + b) * 256 + s];
  fxsh[s + 128] = fxs[((size_t)i * 16 + b) * 256 + s + 128];
  __syncthreads();
  float a = b_skip[i * 128 + s];
  const float* wp = wskT + (size_t)i * 256 * 128 + s;
  #pragma unroll 4
  for (int c = 0; c < 256; c++)
    a = fmaf(wp[c * 128], fxsh[c], a);
  part[((size_t)i * 16 + b) * 128 + s] = a;
}

__global__ __launch_bounds__(128) void head2(
    const float* __restrict__ part, const float* __restrict__ w_o1,
    const float* __restrict__ b_o1, const float* __restrict__ w_o2,
    const float* __restrict__ b_o2, const float* __restrict__ w_lin,
    const float* __restrict__ b_lin, const float* __restrict__ Xex,
    float* __restrict__ out)
{
  int b = blockIdx.x, tid = threadIdx.x;
  __shared__ float sk[128];
  __shared__ float h1[64];
  __shared__ float hc[80];
  float a = 0.f;
  for (int i = 0; i < 32; i++) a += part[((size_t)i * 16 + b) * 128 + tid];
  sk[tid] = fmaxf(a, 0.f);
  __syncthreads();
  if (tid < 64) {
    float a1 = b_o1[tid];
    for (int s = 0; s < 128; s++) a1 = fmaf(w_o1[tid * 128 + s], sk[s], a1);
    h1[tid] = fmaxf(a1, 0.f);
  }
  __syncthreads();
  if (tid < 64) {
    float a2 = b_o2[tid];
    for (int j = 0; j < 64; j++) a2 = fmaf(w_o2[tid * 64 + j], h1[j], a2);
    hc[tid] = fmaxf(a2, 0.f);
  }
  if (tid >= 64 && tid < 80) hc[tid] = fmaxf(Xex[b * 16 + (tid - 64)], 0.f);
  __syncthreads();
  if (tid < 24) {
    float a3 = b_lin[tid];
    for (int j = 0; j < 80; j++) a3 = fmaf(w_lin[tid * 80 + j], hc[j], a3);
    out[b * 24 + tid] = a3;
  }
}

extern "C" void kernel_launch(void* const* d_in, const int* in_sizes, int n_in,
                              void* d_out, int out_size, void* d_ws, size_t ws_size,
                              hipStream_t stream)
{
  (void)in_sizes; (void)n_in; (void)out_size; (void)ws_size;
  const float* X     = (const float*)d_in[0];
  const float* Xex   = (const float*)d_in[1];
  const float* w_in  = (const float*)d_in[2];
  const float* b_in  = (const float*)d_in[3];
  const float* w_f   = (const float*)d_in[4];
  const float* b_f   = (const float*)d_in[5];
  const float* w_g   = (const float*)d_in[6];
  const float* b_g   = (const float*)d_in[7];
  const float* w_r   = (const float*)d_in[8];
  const float* b_r   = (const float*)d_in[9];
  const float* w_s   = (const float*)d_in[10];
  const float* b_s   = (const float*)d_in[11];
  const float* w_o1  = (const float*)d_in[12];
  const float* b_o1  = (const float*)d_in[13];
  const float* w_o2  = (const float*)d_in[14];
  const float* b_o2  = (const float*)d_in[15];
  const float* w_lin = (const float*)d_in[16];
  const float* b_lin = (const float*)d_in[17];

  float* ws   = (float*)d_ws;
  float* wskT = ws;                        // 1,048,576 f
  float* fxs  = wskT + 1048576;            // 131,072 f
  float* part = fxs  + 131072;             // 65,536 f
  float* w2   = part + 65536;              // 16,384 f
  unsigned short* Wb   = (unsigned short*)(w2 + 16384);    // 8,388,608 us
  unsigned short* Wrb  = Wb   + 8388608;   // 2,097,152 us
  unsigned short* xbbA = Wrb  + 2097152;   // 4,194,304 us
  unsigned short* xbbB = xbbA + 4194304;   // 4,194,304 us
  unsigned short* xlo  = xbbB + 4194304;   // 4,194,304 us

  prep<<<22592, 256, 0, stream>>>(w_f, w_g, w_r, w_s, w_in, Wb, Wrb, wskT, w2);
  in_conv<<<1024, 256, 0, stream>>>(X, w2, b_in, xbbA, xlo);

  // suffix-window sizes: w[i] = w[i+1] + 2^(i%8), w[32] = 1
  static const int wI[33] = {1021,1020,1018,1014,1006,990,958,894,
                             766,765,763,759,751,735,703,639,
                             511,510,508,504,496,480,448,384,
                             256,255,253,249,241,225,193,129,1};
  for (int i = 0; i < 32; i++) {
    int dd    = 1 << (i & 7);
    int Wout  = wI[i + 1];
    int t_lo  = TBUF - Wout;
    int tiles = (Wout + 63) / 64;
    unsigned short* xin  = (i & 1) ? xbbB : xbbA;
    unsigned short* xout = (i & 1) ? xbbA : xbbB;
    layer_fused<<<tiles * 16, 1024, 0, stream>>>(
        xin, xout, xlo,
        Wb + (size_t)i * 512 * 512, Wrb + (size_t)i * 256 * 256,
        b_f + i * 256, b_g + i * 256, b_r + i * 256,
        dd, t_lo, fxs + (size_t)i * 16 * 256);
  }
  skip_partial<<<dim3(32, 16), 128, 0, stream>>>(fxs, wskT, b_s, part);
  head2<<<16, 128, 0, stream>>>(part, w_o1, b_o1, w_o2, b_o2, w_lin, b_lin, Xex, (float*)d_out);
}

// Round 15
// 904.819 us; speedup vs baseline: 1.4017x; 1.1027x over previous
//
#include <hip/hip_runtime.h>
#include <cmath>

#define TBUF 1024
#define RCH  256

typedef __bf16 bf16x8 __attribute__((ext_vector_type(8)));
typedef float  f32x4  __attribute__((ext_vector_type(4)));

__device__ inline unsigned short f2bf(float f) {
  unsigned u = __builtin_bit_cast(unsigned, f);
  u += 0x7FFFu + ((u >> 16) & 1u);
  return (unsigned short)(u >> 16);
}
__device__ inline float bf2f(unsigned short h) {
  unsigned u = ((unsigned)h) << 16;
  return __builtin_bit_cast(float, u);
}

// ---------------- merged weight transforms (one dispatch) ----------------
__global__ __launch_bounds__(256) void prep(
    const float* __restrict__ wf, const float* __restrict__ wg,
    const float* __restrict__ wr, const float* __restrict__ wsk,
    const float* __restrict__ w_in,
    unsigned short* __restrict__ Wb, unsigned short* __restrict__ Wrb,
    float* __restrict__ wskT, float* __restrict__ w2)
{
  const int bid = blockIdx.x;
  const int tid = threadIdx.x;
  if (bid < 16384) {
    int idx = bid * 256 + tid;
    int c  = idx & 255;
    int op = (idx >> 8) & 511;
    int i  = idx >> 17;
    int o  = op & 255;
    const float* src = (op < 256) ? wf : wg;
    const float2 v = *(const float2*)&src[(((size_t)i * 256 + o) * 256 + c) << 1];
    unsigned short* dst = Wb + ((size_t)i * 512 + op) * 512;
    dst[c]       = f2bf(v.y);   // current tap (k=1)
    dst[256 + c] = f2bf(v.x);   // previous tap (k=0)
  } else if (bid < 18432) {
    int idx = (bid - 16384) * 256 + tid;
    float4 v = ((const float4*)wr)[idx];
    uint2 o;
    o.x = (unsigned)f2bf(v.x) | ((unsigned)f2bf(v.y) << 16);
    o.y = (unsigned)f2bf(v.z) | ((unsigned)f2bf(v.w) << 16);
    ((uint2*)Wrb)[idx] = o;
  } else if (bid < 22528) {
    int idx = (bid - 18432) * 256 + tid;
    int s = idx & 127;
    int c = (idx >> 7) & 255;
    int i = idx >> 15;
    wskT[idx] = wsk[(i * 128 + s) * 256 + c];
  } else {
    int idx = (bid - 22528) * 256 + tid;
    int r = idx & 255;
    int fk = idx >> 8;
    int f = fk & 31, k = fk >> 5;
    w2[idx] = w_in[r * 64 + f * 2 + k];
  }
}

// ---------------- input conv (F=32 -> R=256, K=2, d=1) ----------------
__global__ __launch_bounds__(256) void in_conv(
    const float* __restrict__ X, const float* __restrict__ w2,
    const float* __restrict__ b_in, unsigned short* __restrict__ xbb,
    unsigned short* __restrict__ xlo)
{
  const int bid   = blockIdx.x;
  const int b     = bid & 15;
  const int chunk = bid >> 4;
  const int r     = threadIdx.x;
  __shared__ float Xs[17][32];
  const int tt0 = chunk << 4;
  const int t0  = tt0 + 1024;
  for (int idx = r; idx < 17 * 32; idx += 256) {
    int row = idx >> 5, f = idx & 31;
    Xs[row][f] = X[((size_t)b * 2048 + (t0 - 1 + row)) * 32 + f];
  }
  __syncthreads();
  float w0[32], w1[32];
  #pragma unroll
  for (int f = 0; f < 32; ++f) {
    w0[f] = w2[f * 256 + r];
    w1[f] = w2[(32 + f) * 256 + r];
  }
  const float bias = b_in[r];
  float4 prev[8], cur[8];
  #pragma unroll
  for (int q = 0; q < 8; ++q) prev[q] = *(const float4*)&Xs[0][q * 4];
  #pragma unroll
  for (int j = 0; j < 16; ++j) {
    #pragma unroll
    for (int q = 0; q < 8; ++q) cur[q] = *(const float4*)&Xs[j + 1][q * 4];
    float a = bias;
    #pragma unroll
    for (int q = 0; q < 8; ++q) {
      a = fmaf(w0[q*4+0], prev[q].x, a); a = fmaf(w1[q*4+0], cur[q].x, a);
      a = fmaf(w0[q*4+1], prev[q].y, a); a = fmaf(w1[q*4+1], cur[q].y, a);
      a = fmaf(w0[q*4+2], prev[q].z, a); a = fmaf(w1[q*4+2], cur[q].z, a);
      a = fmaf(w0[q*4+3], prev[q].w, a); a = fmaf(w1[q*4+3], cur[q].w, a);
    }
    int tt = tt0 + j;
    size_t off = ((size_t)b * TBUF + tt) * RCH + r;
    if (tt < 3) { xbb[off] = 0; xlo[off] = 0; }
    else {
      unsigned short hn = f2bf(a);
      xbb[off] = hn;
      xlo[off] = f2bf(a - bf2f(hn));
    }
    #pragma unroll
    for (int q = 0; q < 8; ++q) prev[q] = cur[q];
  }
}

// ---------------- fused layer, adaptive M = NM*16 rows per block -------------
// 1024 thr = 16 waves. Wave w owns 16 f-cols + 16 g-cols (conv), 16 cols (res).
// Split-precision residual (hi/lo bf16); hi_old re-read from A-tile LDS.
// Res-B IN-LOOP (hoist -> scratch, r4/r8/r12). NM chosen so grid ~ 256 blocks.
template<int NM>
__global__ __launch_bounds__(1024, 4) void layer_fused(
    const unsigned short* __restrict__ xbb_r, unsigned short* __restrict__ xbb_w,
    unsigned short* __restrict__ xlo,
    const unsigned short* __restrict__ Wb,   // [512][512] bf16
    const unsigned short* __restrict__ Wrb,  // [256][256] bf16
    const float* __restrict__ bF, const float* __restrict__ bG,
    const float* __restrict__ bR,
    int dd, int t_lo, float* __restrict__ fxs_i)
{
  __shared__ __align__(16) unsigned short As[NM * 16 * 520];  // z aliases
  const int bid  = blockIdx.x;
  const int b    = bid & 15;
  const int tile = bid >> 4;
  const int tid  = threadIdx.x;
  const int w    = tid >> 6;          // 0..15
  const int lane = tid & 63;
  const int l15  = lane & 15;
  const int lk8  = (lane >> 4) << 3;
  const int rr0  = (lane >> 4) << 2;
  const int tt0  = t_lo + tile * (NM * 16);
  const unsigned short* xB = xbb_r + ((size_t)b << 18);

  // ---- stage A tile via global_load_lds: NM*16 rows x 512 k (NM rows/wave)
  {
    const int c   = lane;
    const int tap = c >> 5;
    const int cg  = (c & 31) << 3;
    #pragma unroll
    for (int it = 0; it < NM; ++it) {
      int r = it * 16 + w;
      int tt = tt0 + r - tap * dd;
      tt = min(max(tt, 0), 1023);
      __builtin_amdgcn_global_load_lds(
          (const __attribute__((address_space(1))) unsigned int*)
              (xB + ((size_t)tt << 8) + cg),
          (__attribute__((address_space(3))) unsigned int*)
              ((char*)As + r * 1040),
          16, 0, 0);
    }
  }
  __syncthreads();

  // ---- conv GEMM: per wave (NM*16)(M) x {16 f + 16 g}
  f32x4 accf[NM] = {};
  f32x4 accg[NM] = {};
  const unsigned short* wf0 = Wb + (size_t)(16 * w + l15) * 512 + lk8;
  const unsigned short* wg0 = wf0 + (size_t)256 * 512;
  #pragma unroll 4
  for (int kc = 0; kc < 16; ++kc) {
    const int k0 = kc * 32;
    uint4 ubf0 = *(const uint4*)(wf0 + k0);
    uint4 ubg0 = *(const uint4*)(wg0 + k0);
    const int colb = (k0 + lk8) * 2;
    bf16x8 a[NM];
    #pragma unroll
    for (int mf = 0; mf < NM; ++mf)
      a[mf] = *(const bf16x8*)((const char*)As + (mf * 16 + l15) * 1040 + colb);
    bf16x8 vf0 = __builtin_bit_cast(bf16x8, ubf0);
    bf16x8 vg0 = __builtin_bit_cast(bf16x8, ubg0);
    #pragma unroll
    for (int mf = 0; mf < NM; ++mf) {
      accf[mf] = __builtin_amdgcn_mfma_f32_16x16x32_bf16(a[mf], vf0, accf[mf], 0, 0, 0);
      accg[mf] = __builtin_amdgcn_mfma_f32_16x16x32_bf16(a[mf], vg0, accg[mf], 0, 0, 0);
    }
  }

  // ---- re-read hi_old from the A-tile LDS (tap-0 region) BEFORE z overwrite
  const int col = 16 * w + l15;
  float hi_pre[NM][4];
  #pragma unroll
  for (int mf = 0; mf < NM; ++mf)
    #pragma unroll
    for (int j = 0; j < 4; ++j) {
      int row = mf * 16 + rr0 + j;
      hi_pre[mf][j] = bf2f(*(const unsigned short*)((const char*)As + row * 1040 + col * 2));
    }
  __syncthreads();   // all As reads done -> safe to overwrite with z

  // ---- gate epilogue: z = tanh(f+bf) * sigmoid(g+bg) -> LDS (aliased)
  unsigned short* Zs = As;
  const float bfv = bF[col];
  const float bgv = bG[col];
  #pragma unroll
  for (int mf = 0; mf < NM; ++mf)
    #pragma unroll
    for (int j = 0; j < 4; ++j) {
      int row = mf * 16 + rr0 + j;
      float pf = accf[mf][j] + bfv;
      float pg = accg[mf][j] + bgv;
      float e2 = __expf(2.f * pf);
      float th = 1.f - 2.f / (e2 + 1.f);
      float sg = 1.f / (1.f + __expf(-pg));
      *(unsigned short*)((char*)Zs + row * 528 + col * 2) = f2bf(th * sg);
    }
  __syncthreads();

  // ---- hoist lo_old loads (independent of z; latency hides under res GEMM)
  unsigned short* xL = xlo + ((size_t)b << 18);
  float lo_pre[NM][4];
  #pragma unroll
  for (int mf = 0; mf < NM; ++mf)
    #pragma unroll
    for (int j = 0; j < 4; ++j) {
      int tt = min(tt0 + mf * 16 + rr0 + j, 1023);
      lo_pre[mf][j] = bf2f(xL[((size_t)tt << 8) + col]);
    }

  // ---- res GEMM: per wave (NM*16)(M) x 16(N), K=256 from z-LDS (B in-loop)
  f32x4 acc[NM] = {};
  const unsigned short* wr0 = Wrb + (size_t)(16 * w + l15) * 256 + lk8;
  #pragma unroll 4
  for (int kc = 0; kc < 8; ++kc) {
    uint4 ur0 = *(const uint4*)(wr0 + kc * 32);
    const int colb = (kc * 32 + lk8) * 2;
    bf16x8 a[NM];
    #pragma unroll
    for (int mf = 0; mf < NM; ++mf)
      a[mf] = *(const bf16x8*)((const char*)Zs + (mf * 16 + l15) * 528 + colb);
    bf16x8 v0 = __builtin_bit_cast(bf16x8, ur0);
    #pragma unroll
    for (int mf = 0; mf < NM; ++mf)
      acc[mf] = __builtin_amdgcn_mfma_f32_16x16x32_bf16(a[mf], v0, acc[mf], 0, 0, 0);
  }

  // ---- residual epilogue: xn = (hi+lo) + fx; re-split to hi'/lo'; fx snapshot
  const float brv = bR[col];
  unsigned short* xBb = xbb_w + ((size_t)b << 18);
  #pragma unroll
  for (int mf = 0; mf < NM; ++mf)
    #pragma unroll
    for (int j = 0; j < 4; ++j) {
      int tt = tt0 + mf * 16 + rr0 + j;
      if (tt > 1023) continue;
      size_t off = ((size_t)tt << 8) + col;
      float fx = acc[mf][j] + brv;
      float xn = (hi_pre[mf][j] + lo_pre[mf][j]) + fx;
      unsigned short hn = f2bf(xn);
      xBb[off] = hn;
      xL[off]  = f2bf(xn - bf2f(hn));
      if (tt == 1023) fxs_i[(size_t)b * 256 + col] = fx;
    }
}

// ---------------- head ----------------
__global__ __launch_bounds__(128) void skip_partial(
    const float* __restrict__ fxs, const float* __restrict__ wskT,
    const float* __restrict__ b_skip, float* __restrict__ part)
{
  int i = blockIdx.x, b = blockIdx.y, s = threadIdx.x;
  __shared__ float fxsh[256];
  fxsh[s]       = fxs[((size_t)i * 16 + b) * 256 + s];
  fxsh[s + 128] = fxs[((size_t)i * 16 + b) * 256 + s + 128];
  __syncthreads();
  float a = b_skip[i * 128 + s];
  const float* wp = wskT + (size_t)i * 256 * 128 + s;
  #pragma unroll 4
  for (int c = 0; c < 256; c++)
    a = fmaf(wp[c * 128], fxsh[c], a);
  part[((size_t)i * 16 + b) * 128 + s] = a;
}

__global__ __launch_bounds__(128) void head2(
    const float* __restrict__ part, const float* __restrict__ w_o1,
    const float* __restrict__ b_o1, const float* __restrict__ w_o2,
    const float* __restrict__ b_o2, const float* __restrict__ w_lin,
    const float* __restrict__ b_lin, const float* __restrict__ Xex,
    float* __restrict__ out)
{
  int b = blockIdx.x, tid = threadIdx.x;
  __shared__ float sk[128];
  __shared__ float h1[64];
  __shared__ float hc[80];
  float a = 0.f;
  for (int i = 0; i < 32; i++) a += part[((size_t)i * 16 + b) * 128 + tid];
  sk[tid] = fmaxf(a, 0.f);
  __syncthreads();
  if (tid < 64) {
    float a1 = b_o1[tid];
    for (int s = 0; s < 128; s++) a1 = fmaf(w_o1[tid * 128 + s], sk[s], a1);
    h1[tid] = fmaxf(a1, 0.f);
  }
  __syncthreads();
  if (tid < 64) {
    float a2 = b_o2[tid];
    for (int j = 0; j < 64; j++) a2 = fmaf(w_o2[tid * 64 + j], h1[j], a2);
    hc[tid] = fmaxf(a2, 0.f);
  }
  if (tid >= 64 && tid < 80) hc[tid] = fmaxf(Xex[b * 16 + (tid - 64)], 0.f);
  __syncthreads();
  if (tid < 24) {
    float a3 = b_lin[tid];
    for (int j = 0; j < 80; j++) a3 = fmaf(w_lin[tid * 80 + j], hc[j], a3);
    out[b * 24 + tid] = a3;
  }
}

extern "C" void kernel_launch(void* const* d_in, const int* in_sizes, int n_in,
                              void* d_out, int out_size, void* d_ws, size_t ws_size,
                              hipStream_t stream)
{
  (void)in_sizes; (void)n_in; (void)out_size; (void)ws_size;
  const float* X     = (const float*)d_in[0];
  const float* Xex   = (const float*)d_in[1];
  const float* w_in  = (const float*)d_in[2];
  const float* b_in  = (const float*)d_in[3];
  const float* w_f   = (const float*)d_in[4];
  const float* b_f   = (const float*)d_in[5];
  const float* w_g   = (const float*)d_in[6];
  const float* b_g   = (const float*)d_in[7];
  const float* w_r   = (const float*)d_in[8];
  const float* b_r   = (const float*)d_in[9];
  const float* w_s   = (const float*)d_in[10];
  const float* b_s   = (const float*)d_in[11];
  const float* w_o1  = (const float*)d_in[12];
  const float* b_o1  = (const float*)d_in[13];
  const float* w_o2  = (const float*)d_in[14];
  const float* b_o2  = (const float*)d_in[15];
  const float* w_lin = (const float*)d_in[16];
  const float* b_lin = (const float*)d_in[17];

  float* ws   = (float*)d_ws;
  float* wskT = ws;                        // 1,048,576 f
  float* fxs  = wskT + 1048576;            // 131,072 f
  float* part = fxs  + 131072;             // 65,536 f
  float* w2   = part + 65536;              // 16,384 f
  unsigned short* Wb   = (unsigned short*)(w2 + 16384);    // 8,388,608 us
  unsigned short* Wrb  = Wb   + 8388608;   // 2,097,152 us
  unsigned short* xbbA = Wrb  + 2097152;   // 4,194,304 us
  unsigned short* xbbB = xbbA + 4194304;   // 4,194,304 us
  unsigned short* xlo  = xbbB + 4194304;   // 4,194,304 us

  prep<<<22592, 256, 0, stream>>>(w_f, w_g, w_r, w_s, w_in, Wb, Wrb, wskT, w2);
  in_conv<<<1024, 256, 0, stream>>>(X, w2, b_in, xbbA, xlo);

  // suffix-window sizes: w[i] = w[i+1] + 2^(i%8), w[32] = 1
  static const int wI[33] = {1021,1020,1018,1014,1006,990,958,894,
                             766,765,763,759,751,735,703,639,
                             511,510,508,504,496,480,448,384,
                             256,255,253,249,241,225,193,129,1};
  for (int i = 0; i < 32; i++) {
    int dd    = 1 << (i & 7);
    int Wout  = wI[i + 1];
    int t_lo  = TBUF - Wout;
    unsigned short* xin  = (i & 1) ? xbbB : xbbA;
    unsigned short* xout = (i & 1) ? xbbA : xbbB;
    const unsigned short* WbL  = Wb  + (size_t)i * 512 * 512;
    const unsigned short* WrbL = Wrb + (size_t)i * 256 * 256;
    const float* bFi = b_f + i * 256;
    const float* bGi = b_g + i * 256;
    const float* bRi = b_r + i * 256;
    float* fxi = fxs + (size_t)i * 16 * 256;
    // Adaptive M: keep grid near 256 blocks without exceeding 1 round.
    if (Wout >= 520) {
      int tiles = (Wout + 63) / 64;
      layer_fused<4><<<tiles * 16, 1024, 0, stream>>>(
          xin, xout, xlo, WbL, WrbL, bFi, bGi, bRi, dd, t_lo, fxi);
    } else if (Wout >= 260) {
      int tiles = (Wout + 31) / 32;
      layer_fused<2><<<tiles * 16, 1024, 0, stream>>>(
          xin, xout, xlo, WbL, WrbL, bFi, bGi, bRi, dd, t_lo, fxi);
    } else {
      int tiles = (Wout + 15) / 16;
      layer_fused<1><<<tiles * 16, 1024, 0, stream>>>(
          xin, xout, xlo, WbL, WrbL, bFi, bGi, bRi, dd, t_lo, fxi);
    }
  }
  skip_partial<<<dim3(32, 16), 128, 0, stream>>>(fxs, wskT, b_s, part);
  head2<<<16, 128, 0, stream>>>(part, w_o1, b_o1, w_o2, b_o2, w_lin, b_lin, Xex, (float*)d_out);
}

// Round 16
// 883.027 us; speedup vs baseline: 1.4363x; 1.0247x over previous
//
#include <hip/hip_runtime.h>
#include <cmath>

#define TBUF 1024
#define RCH  256

typedef __bf16 bf16x8 __attribute__((ext_vector_type(8)));
typedef float  f32x4  __attribute__((ext_vector_type(4)));

__device__ inline unsigned short f2bf(float f) {
  unsigned u = __builtin_bit_cast(unsigned, f);
  u += 0x7FFFu + ((u >> 16) & 1u);
  return (unsigned short)(u >> 16);
}
__device__ inline float bf2f(unsigned short h) {
  unsigned u = ((unsigned)h) << 16;
  return __builtin_bit_cast(float, u);
}

// ---------------- merged weight transforms (one dispatch) ----------------
__global__ __launch_bounds__(256) void prep(
    const float* __restrict__ wf, const float* __restrict__ wg,
    const float* __restrict__ wr, const float* __restrict__ wsk,
    const float* __restrict__ w_in,
    unsigned short* __restrict__ Wb, unsigned short* __restrict__ Wrb,
    float* __restrict__ wskT, float* __restrict__ w2)
{
  const int bid = blockIdx.x;
  const int tid = threadIdx.x;
  if (bid < 16384) {
    int idx = bid * 256 + tid;
    int c  = idx & 255;
    int op = (idx >> 8) & 511;
    int i  = idx >> 17;
    int o  = op & 255;
    const float* src = (op < 256) ? wf : wg;
    const float2 v = *(const float2*)&src[(((size_t)i * 256 + o) * 256 + c) << 1];
    unsigned short* dst = Wb + ((size_t)i * 512 + op) * 512;
    dst[c]       = f2bf(v.y);   // current tap (k=1)
    dst[256 + c] = f2bf(v.x);   // previous tap (k=0)
  } else if (bid < 18432) {
    int idx = (bid - 16384) * 256 + tid;
    float4 v = ((const float4*)wr)[idx];
    uint2 o;
    o.x = (unsigned)f2bf(v.x) | ((unsigned)f2bf(v.y) << 16);
    o.y = (unsigned)f2bf(v.z) | ((unsigned)f2bf(v.w) << 16);
    ((uint2*)Wrb)[idx] = o;
  } else if (bid < 22528) {
    int idx = (bid - 18432) * 256 + tid;
    int s = idx & 127;
    int c = (idx >> 7) & 255;
    int i = idx >> 15;
    wskT[idx] = wsk[(i * 128 + s) * 256 + c];
  } else {
    int idx = (bid - 22528) * 256 + tid;
    int r = idx & 255;
    int fk = idx >> 8;
    int f = fk & 31, k = fk >> 5;
    w2[idx] = w_in[r * 64 + f * 2 + k];
  }
}

// ---------------- input conv (F=32 -> R=256, K=2, d=1) ----------------
__global__ __launch_bounds__(256) void in_conv(
    const float* __restrict__ X, const float* __restrict__ w2,
    const float* __restrict__ b_in, unsigned short* __restrict__ xbb,
    unsigned short* __restrict__ xlo)
{
  const int bid   = blockIdx.x;
  const int b     = bid & 15;
  const int chunk = bid >> 4;
  const int r     = threadIdx.x;
  __shared__ float Xs[17][32];
  const int tt0 = chunk << 4;
  const int t0  = tt0 + 1024;
  for (int idx = r; idx < 17 * 32; idx += 256) {
    int row = idx >> 5, f = idx & 31;
    Xs[row][f] = X[((size_t)b * 2048 + (t0 - 1 + row)) * 32 + f];
  }
  __syncthreads();
  float w0[32], w1[32];
  #pragma unroll
  for (int f = 0; f < 32; ++f) {
    w0[f] = w2[f * 256 + r];
    w1[f] = w2[(32 + f) * 256 + r];
  }
  const float bias = b_in[r];
  float4 prev[8], cur[8];
  #pragma unroll
  for (int q = 0; q < 8; ++q) prev[q] = *(const float4*)&Xs[0][q * 4];
  #pragma unroll
  for (int j = 0; j < 16; ++j) {
    #pragma unroll
    for (int q = 0; q < 8; ++q) cur[q] = *(const float4*)&Xs[j + 1][q * 4];
    float a = bias;
    #pragma unroll
    for (int q = 0; q < 8; ++q) {
      a = fmaf(w0[q*4+0], prev[q].x, a); a = fmaf(w1[q*4+0], cur[q].x, a);
      a = fmaf(w0[q*4+1], prev[q].y, a); a = fmaf(w1[q*4+1], cur[q].y, a);
      a = fmaf(w0[q*4+2], prev[q].z, a); a = fmaf(w1[q*4+2], cur[q].z, a);
      a = fmaf(w0[q*4+3], prev[q].w, a); a = fmaf(w1[q*4+3], cur[q].w, a);
    }
    int tt = tt0 + j;
    size_t off = ((size_t)b * TBUF + tt) * RCH + r;
    if (tt < 3) { xbb[off] = 0; xlo[off] = 0; }
    else {
      unsigned short hn = f2bf(a);
      xbb[off] = hn;
      xlo[off] = f2bf(a - bf2f(hn));
    }
    #pragma unroll
    for (int q = 0; q < 8; ++q) prev[q] = cur[q];
  }
}

// ---------------- fused layer, adaptive M = NM*16 rows per block -------------
// 1024 thr = 16 waves. Wave w owns 16 f-cols + 16 g-cols (conv), 16 cols (res).
// Split-precision residual (hi/lo bf16); hi_old re-read from A-tile LDS.
// NM = ceil(W/256) -> smallest per-block work with grid <= 256.
// 1-deep weight ping-pong; kc=0 weights + lo_pre issued pre-barrier so their
// latency overlaps the gload_lds drain / gate epilogue. Only small scalars are
// held across barriers (the 64-VGPR array hoist spills: r4/r8/r12).
template<int NM>
__global__ __launch_bounds__(1024, 4) void layer_fused(
    const unsigned short* __restrict__ xbb_r, unsigned short* __restrict__ xbb_w,
    unsigned short* __restrict__ xlo,
    const unsigned short* __restrict__ Wb,   // [512][512] bf16
    const unsigned short* __restrict__ Wrb,  // [256][256] bf16
    const float* __restrict__ bF, const float* __restrict__ bG,
    const float* __restrict__ bR,
    int dd, int t_lo, float* __restrict__ fxs_i)
{
  __shared__ __align__(16) unsigned short As[NM * 16 * 520];  // z aliases
  const int bid  = blockIdx.x;
  const int b    = bid & 15;
  const int tile = bid >> 4;
  const int tid  = threadIdx.x;
  const int w    = tid >> 6;          // 0..15
  const int lane = tid & 63;
  const int l15  = lane & 15;
  const int lk8  = (lane >> 4) << 3;
  const int rr0  = (lane >> 4) << 2;
  const int tt0  = t_lo + tile * (NM * 16);
  const unsigned short* xB = xbb_r + ((size_t)b << 18);

  // ---- stage A tile via global_load_lds: NM*16 rows x 512 k (NM rows/wave)
  {
    const int c   = lane;
    const int tap = c >> 5;
    const int cg  = (c & 31) << 3;
    #pragma unroll
    for (int it = 0; it < NM; ++it) {
      int r = it * 16 + w;
      int tt = tt0 + r - tap * dd;
      tt = min(max(tt, 0), 1023);
      __builtin_amdgcn_global_load_lds(
          (const __attribute__((address_space(1))) unsigned int*)
              (xB + ((size_t)tt << 8) + cg),
          (__attribute__((address_space(3))) unsigned int*)
              ((char*)As + r * 1040),
          16, 0, 0);
    }
  }

  // ---- preload first conv/res weight chunks BEFORE the barrier:
  //      their L2 latency overlaps the gload_lds drain.
  const unsigned short* wf0 = Wb + (size_t)(16 * w + l15) * 512 + lk8;
  const unsigned short* wg0 = wf0 + (size_t)256 * 512;
  const unsigned short* wr0 = Wrb + (size_t)(16 * w + l15) * 256 + lk8;
  uint4 nbf = *(const uint4*)(wf0);
  uint4 nbg = *(const uint4*)(wg0);
  uint4 nr0 = *(const uint4*)(wr0);
  __syncthreads();

  // ---- conv GEMM: per wave (NM*16)(M) x {16 f + 16 g}, 1-deep B ping-pong
  f32x4 accf[NM] = {};
  f32x4 accg[NM] = {};
  #pragma unroll 4
  for (int kc = 0; kc < 16; ++kc) {
    uint4 cbf = nbf, cbg = nbg;
    if (kc < 15) {
      nbf = *(const uint4*)(wf0 + (kc + 1) * 32);
      nbg = *(const uint4*)(wg0 + (kc + 1) * 32);
    }
    const int colb = (kc * 32 + lk8) * 2;
    bf16x8 a[NM];
    #pragma unroll
    for (int mf = 0; mf < NM; ++mf)
      a[mf] = *(const bf16x8*)((const char*)As + (mf * 16 + l15) * 1040 + colb);
    bf16x8 vf0 = __builtin_bit_cast(bf16x8, cbf);
    bf16x8 vg0 = __builtin_bit_cast(bf16x8, cbg);
    #pragma unroll
    for (int mf = 0; mf < NM; ++mf) {
      accf[mf] = __builtin_amdgcn_mfma_f32_16x16x32_bf16(a[mf], vf0, accf[mf], 0, 0, 0);
      accg[mf] = __builtin_amdgcn_mfma_f32_16x16x32_bf16(a[mf], vg0, accg[mf], 0, 0, 0);
    }
  }

  // ---- re-read hi_old from the A-tile LDS (tap-0 region) BEFORE z overwrite
  const int col = 16 * w + l15;
  float hi_pre[NM][4];
  #pragma unroll
  for (int mf = 0; mf < NM; ++mf)
    #pragma unroll
    for (int j = 0; j < 4; ++j) {
      int row = mf * 16 + rr0 + j;
      hi_pre[mf][j] = bf2f(*(const unsigned short*)((const char*)As + row * 1040 + col * 2));
    }

  // ---- lo_old loads issued HERE (independent of z; latency hides under
  //      gate epilogue + barrier + res GEMM)
  unsigned short* xL = xlo + ((size_t)b << 18);
  float lo_pre[NM][4];
  #pragma unroll
  for (int mf = 0; mf < NM; ++mf)
    #pragma unroll
    for (int j = 0; j < 4; ++j) {
      int tt = min(tt0 + mf * 16 + rr0 + j, 1023);
      lo_pre[mf][j] = bf2f(xL[((size_t)tt << 8) + col]);
    }
  __syncthreads();   // all As reads done -> safe to overwrite with z

  // ---- gate epilogue: z = tanh(f+bf) * sigmoid(g+bg) -> LDS (aliased)
  unsigned short* Zs = As;
  const float bfv = bF[col];
  const float bgv = bG[col];
  #pragma unroll
  for (int mf = 0; mf < NM; ++mf)
    #pragma unroll
    for (int j = 0; j < 4; ++j) {
      int row = mf * 16 + rr0 + j;
      float pf = accf[mf][j] + bfv;
      float pg = accg[mf][j] + bgv;
      float e2 = __expf(2.f * pf);
      float th = 1.f - 2.f / (e2 + 1.f);
      float sg = 1.f / (1.f + __expf(-pg));
      *(unsigned short*)((char*)Zs + row * 528 + col * 2) = f2bf(th * sg);
    }
  __syncthreads();

  // ---- res GEMM: per wave (NM*16)(M) x 16(N), K=256, 1-deep B ping-pong
  f32x4 acc[NM] = {};
  #pragma unroll 4
  for (int kc = 0; kc < 8; ++kc) {
    uint4 cr0 = nr0;
    if (kc < 7) nr0 = *(const uint4*)(wr0 + (kc + 1) * 32);
    const int colb = (kc * 32 + lk8) * 2;
    bf16x8 a[NM];
    #pragma unroll
    for (int mf = 0; mf < NM; ++mf)
      a[mf] = *(const bf16x8*)((const char*)Zs + (mf * 16 + l15) * 528 + colb);
    bf16x8 v0 = __builtin_bit_cast(bf16x8, cr0);
    #pragma unroll
    for (int mf = 0; mf < NM; ++mf)
      acc[mf] = __builtin_amdgcn_mfma_f32_16x16x32_bf16(a[mf], v0, acc[mf], 0, 0, 0);
  }

  // ---- residual epilogue: xn = (hi+lo) + fx; re-split to hi'/lo'; fx snapshot
  const float brv = bR[col];
  unsigned short* xBb = xbb_w + ((size_t)b << 18);
  #pragma unroll
  for (int mf = 0; mf < NM; ++mf)
    #pragma unroll
    for (int j = 0; j < 4; ++j) {
      int tt = tt0 + mf * 16 + rr0 + j;
      if (tt > 1023) continue;
      size_t off = ((size_t)tt << 8) + col;
      float fx = acc[mf][j] + brv;
      float xn = (hi_pre[mf][j] + lo_pre[mf][j]) + fx;
      unsigned short hn = f2bf(xn);
      xBb[off] = hn;
      xL[off]  = f2bf(xn - bf2f(hn));
      if (tt == 1023) fxs_i[(size_t)b * 256 + col] = fx;
    }
}

// ---------------- head ----------------
__global__ __launch_bounds__(128) void skip_partial(
    const float* __restrict__ fxs, const float* __restrict__ wskT,
    const float* __restrict__ b_skip, float* __restrict__ part)
{
  int i = blockIdx.x, b = blockIdx.y, s = threadIdx.x;
  __shared__ float fxsh[256];
  fxsh[s]       = fxs[((size_t)i * 16 + b) * 256 + s];
  fxsh[s + 128] = fxs[((size_t)i * 16 + b) * 256 + s + 128];
  __syncthreads();
  float a = b_skip[i * 128 + s];
  const float* wp = wskT + (size_t)i * 256 * 128 + s;
  #pragma unroll 4
  for (int c = 0; c < 256; c++)
    a = fmaf(wp[c * 128], fxsh[c], a);
  part[((size_t)i * 16 + b) * 128 + s] = a;
}

__global__ __launch_bounds__(128) void head2(
    const float* __restrict__ part, const float* __restrict__ w_o1,
    const float* __restrict__ b_o1, const float* __restrict__ w_o2,
    const float* __restrict__ b_o2, const float* __restrict__ w_lin,
    const float* __restrict__ b_lin, const float* __restrict__ Xex,
    float* __restrict__ out)
{
  int b = blockIdx.x, tid = threadIdx.x;
  __shared__ float sk[128];
  __shared__ float h1[64];
  __shared__ float hc[80];
  float a = 0.f;
  for (int i = 0; i < 32; i++) a += part[((size_t)i * 16 + b) * 128 + tid];
  sk[tid] = fmaxf(a, 0.f);
  __syncthreads();
  if (tid < 64) {
    float a1 = b_o1[tid];
    for (int s = 0; s < 128; s++) a1 = fmaf(w_o1[tid * 128 + s], sk[s], a1);
    h1[tid] = fmaxf(a1, 0.f);
  }
  __syncthreads();
  if (tid < 64) {
    float a2 = b_o2[tid];
    for (int j = 0; j < 64; j++) a2 = fmaf(w_o2[tid * 64 + j], h1[j], a2);
    hc[tid] = fmaxf(a2, 0.f);
  }
  if (tid >= 64 && tid < 80) hc[tid] = fmaxf(Xex[b * 16 + (tid - 64)], 0.f);
  __syncthreads();
  if (tid < 24) {
    float a3 = b_lin[tid];
    for (int j = 0; j < 80; j++) a3 = fmaf(w_lin[tid * 80 + j], hc[j], a3);
    out[b * 24 + tid] = a3;
  }
}

extern "C" void kernel_launch(void* const* d_in, const int* in_sizes, int n_in,
                              void* d_out, int out_size, void* d_ws, size_t ws_size,
                              hipStream_t stream)
{
  (void)in_sizes; (void)n_in; (void)out_size; (void)ws_size;
  const float* X     = (const float*)d_in[0];
  const float* Xex   = (const float*)d_in[1];
  const float* w_in  = (const float*)d_in[2];
  const float* b_in  = (const float*)d_in[3];
  const float* w_f   = (const float*)d_in[4];
  const float* b_f   = (const float*)d_in[5];
  const float* w_g   = (const float*)d_in[6];
  const float* b_g   = (const float*)d_in[7];
  const float* w_r   = (const float*)d_in[8];
  const float* b_r   = (const float*)d_in[9];
  const float* w_s   = (const float*)d_in[10];
  const float* b_s   = (const float*)d_in[11];
  const float* w_o1  = (const float*)d_in[12];
  const float* b_o1  = (const float*)d_in[13];
  const float* w_o2  = (const float*)d_in[14];
  const float* b_o2  = (const float*)d_in[15];
  const float* w_lin = (const float*)d_in[16];
  const float* b_lin = (const float*)d_in[17];

  float* ws   = (float*)d_ws;
  float* wskT = ws;                        // 1,048,576 f
  float* fxs  = wskT + 1048576;            // 131,072 f
  float* part = fxs  + 131072;             // 65,536 f
  float* w2   = part + 65536;              // 16,384 f
  unsigned short* Wb   = (unsigned short*)(w2 + 16384);    // 8,388,608 us
  unsigned short* Wrb  = Wb   + 8388608;   // 2,097,152 us
  unsigned short* xbbA = Wrb  + 2097152;   // 4,194,304 us
  unsigned short* xbbB = xbbA + 4194304;   // 4,194,304 us
  unsigned short* xlo  = xbbB + 4194304;   // 4,194,304 us

  prep<<<22592, 256, 0, stream>>>(w_f, w_g, w_r, w_s, w_in, Wb, Wrb, wskT, w2);
  in_conv<<<1024, 256, 0, stream>>>(X, w2, b_in, xbbA, xlo);

  // suffix-window sizes: w[i] = w[i+1] + 2^(i%8), w[32] = 1
  static const int wI[33] = {1021,1020,1018,1014,1006,990,958,894,
                             766,765,763,759,751,735,703,639,
                             511,510,508,504,496,480,448,384,
                             256,255,253,249,241,225,193,129,1};
  for (int i = 0; i < 32; i++) {
    int dd    = 1 << (i & 7);
    int Wout  = wI[i + 1];
    int t_lo  = TBUF - Wout;
    unsigned short* xin  = (i & 1) ? xbbB : xbbA;
    unsigned short* xout = (i & 1) ? xbbA : xbbB;
    const unsigned short* WbL  = Wb  + (size_t)i * 512 * 512;
    const unsigned short* WrbL = Wrb + (size_t)i * 256 * 256;
    const float* bFi = b_f + i * 256;
    const float* bGi = b_g + i * 256;
    const float* bRi = b_r + i * 256;
    float* fxi = fxs + (size_t)i * 16 * 256;
    // NM = ceil(W/256): smallest per-block work with grid <= 256 blocks.
    int NM = (Wout + 255) >> 8;
    int tiles = (Wout + NM * 16 - 1) / (NM * 16);
    switch (NM) {
      case 4:
        layer_fused<4><<<tiles * 16, 1024, 0, stream>>>(
            xin, xout, xlo, WbL, WrbL, bFi, bGi, bRi, dd, t_lo, fxi);
        break;
      case 3:
        layer_fused<3><<<tiles * 16, 1024, 0, stream>>>(
            xin, xout, xlo, WbL, WrbL, bFi, bGi, bRi, dd, t_lo, fxi);
        break;
      case 2:
        layer_fused<2><<<tiles * 16, 1024, 0, stream>>>(
            xin, xout, xlo, WbL, WrbL, bFi, bGi, bRi, dd, t_lo, fxi);
        break;
      default:
        layer_fused<1><<<tiles * 16, 1024, 0, stream>>>(
            xin, xout, xlo, WbL, WrbL, bFi, bGi, bRi, dd, t_lo, fxi);
        break;
    }
  }
  skip_partial<<<dim3(32, 16), 128, 0, stream>>>(fxs, wskT, b_s, part);
  head2<<<16, 128, 0, stream>>>(part, w_o1, b_o1, w_o2, b_o2, w_lin, b_lin, Xex, (float*)d_out);
}